// Round 18
// baseline (195.040 us; speedup 1.0000x reference)
//
#include <hip/hip_runtime.h>
#include <math.h>

constexpr int Cc = 3, Hh = 256;
constexpr int NX = 393216;                 // 2*3*256*256
constexpr int R = 8;                       // rows per block
constexpr int NBLK = 192;                  // 6 images * 32 tiles (1 block/CU)
constexpr int KSTEPS = 50;
constexpr int ROWQ = 128;                  // u64 per halo row (256 floats)
constexpr int BROWS = 12;                  // halo rows per block per slot
constexpr int SLOTQ = NBLK * BROWS * ROWQ; // u64 per slot

using u64 = unsigned long long;
constexpr u64 SENT = 0x8000000080000000ull;  // (-0.0f,-0.0f): unreachable payload

__device__ __forceinline__ float4 ld4(const float* p, int i) { return ((const float4*)p)[i]; }
__device__ __forceinline__ void st4(float* p, int i, float4 v) { ((float4*)p)[i] = v; }
__device__ __forceinline__ float4 mk4(float a, float b, float c, float d) { return make_float4(a, b, c, d); }
__device__ __forceinline__ u64 ldq(const u64* p) {
    return __hip_atomic_load(p, __ATOMIC_RELAXED, __HIP_MEMORY_SCOPE_AGENT);
}
__device__ __forceinline__ void stq(u64* p, u64 v) {
    __hip_atomic_store(p, v, __ATOMIC_RELAXED, __HIP_MEMORY_SCOPE_AGENT);
}
__device__ __forceinline__ void pub4(u64* w, float4 v) {
    union { float f[2]; u64 q; } a, b;
    a.f[0] = v.x; a.f[1] = v.y; b.f[0] = v.z; b.f[1] = v.w;
    stq(w, a.q); stq(w + 1, b.q);
}
__device__ __forceinline__ float4 unp(u64 lo, u64 hi) {
    union { u64 q; float f[2]; } a, b; a.q = lo; b.q = hi;
    return make_float4(a.f[0], a.f[1], b.f[0], b.f[1]);
}
__device__ __forceinline__ float4 col3(float4 P, float4 A, float4 B, float a, float b) {
    return mk4(fmaf(a, A.x, fmaf(b, B.x, P.x)), fmaf(a, A.y, fmaf(b, B.y, P.y)),
               fmaf(a, A.z, fmaf(b, B.z, P.z)), fmaf(a, A.w, fmaf(b, B.w, P.w)));
}
__device__ __forceinline__ float4 f4sub(float4 a, float4 b) {
    return mk4(a.x - b.x, a.y - b.y, a.z - b.z, a.w - b.w);
}
__device__ __forceinline__ float4 f4s(float4 a, float s) {
    return mk4(a.x * s, a.y * s, a.z * s, a.w * s);
}
__device__ __forceinline__ float4 f4fma(float s, float4 a, float4 b) {   // s*a + b
    return mk4(fmaf(s, a.x, b.x), fmaf(s, a.y, b.y), fmaf(s, a.z, b.z), fmaf(s, a.w, b.w));
}
__device__ __forceinline__ float4 nth(float4 vm, bool up, float4 v0x, bool dn) {
    return mk4((up ? vm.x : 0.f) - (dn ? v0x.x : 0.f), (up ? vm.y : 0.f) - (dn ? v0x.y : 0.f),
               (up ? vm.z : 0.f) - (dn ? v0x.z : 0.f), (up ? vm.w : 0.f) - (dn ? v0x.w : 0.f));
}
__device__ __forceinline__ float4 ntw(float4 v1x, int c4) {
    float ul = __shfl_up(v1x.w, 1, 64);
    return mk4(((c4 > 0) ? ul : 0.f) - v1x.x, v1x.x - v1x.y, v1x.y - v1x.z,
               v1x.z - ((c4 < 63) ? v1x.w : 0.f));
}
__device__ __forceinline__ float4 gradw(float4 t, int c4) {
    float xn = __shfl_down(t.x, 1, 64);
    return mk4(t.y - t.x, t.z - t.y, t.w - t.z, (c4 < 63) ? (xn - t.w) : 0.f);
}
__device__ __forceinline__ float dot4(float4 a, float4 b) {
    return a.x * b.x + a.y * b.y + a.z * b.z + a.w * b.w;
}
__device__ __forceinline__ void barld() {
    asm volatile("s_waitcnt lgkmcnt(0)" ::: "memory");
    __builtin_amdgcn_sched_barrier(0);
    __builtin_amdgcn_s_barrier();
    __builtin_amdgcn_sched_barrier(0);
}

__global__ void init_ws(u64* h0, u64* h1, u64* h2, u64* parts) {
    int i = blockIdx.x * 256 + threadIdx.x;
    if (i < SLOTQ) { h0[i] = SENT; h1[i] = SENT; h2[i] = SENT; }
    if (i < (KSTEPS + 1) * NBLK) parts[i] = SENT;
}

__global__ void __launch_bounds__(512, 1) cp_persist(
    const float* __restrict__ y, const float* __restrict__ lambd,
    float* __restrict__ xout, float* __restrict__ xtout, float* __restrict__ uout,
    u64* __restrict__ h0, u64* __restrict__ h1, u64* __restrict__ h2,
    u64* __restrict__ parts)
{
    __shared__ float sv0[8 * 256];
    __shared__ float sxtP[8 * 256], sxtA[8 * 256], sxtB[8 * 256];
    __shared__ float2 pw[8];
    __shared__ volatile float sG[2];           // wave-1 broadcast of global norm sums
    __shared__ volatile unsigned sStamp;       // monotonic step stamp for sG

    const int tid = threadIdx.x, blk = blockIdx.x;
    const int bc = blk >> 5, tile = blk & 31, r0 = tile * R;
    const int c4 = tid & 63, trow = tid >> 6;      // one row per wave
    const int b = (bc >= Cc) ? 1 : 0;
    const float lamb = expf(lambd[0]);
    const int gh = r0 + trow;
    const int j4 = bc * 16384 + gh * 64 + c4;

    float4 yv, xcur, v0c, v1c;
    float4 xpP, xpA, xpB, p0P, p0A, p0B, p1P, p1A, p1B;
    float4 yh = mk4(0, 0, 0, 0), vmtop = yh, v0h = yh, v1h = yh, xoh = yh;
    float4 xt8P = yh, xt8A = yh, xt8B = yh;        // wave-7 halo xt pieces (registers)
    float tau = 0.20412414523193150818f, sig = tau, chi = 0.f, sigs = 0.f;
    float g0 = 0.f, g1 = 0.f;

    auto slotp = [&](int r) -> u64* { return (r == 0) ? h0 : ((r == 1) ? h1 : h2); };
    auto wavesum2 = [&](float& a, float& bb) {
        #pragma unroll
        for (int m = 1; m < 64; m <<= 1) { a += __shfl_xor(a, m, 64); bb += __shfl_xor(bb, m, 64); }
    };

    // wide parts poll (wave 1 only): 2 words/lane, fixed-order deterministic sum
    auto pollwide = [&](int s) {
        const u64* pb = parts + (size_t)s * NBLK + b * 96;
        const int i1 = 64 + (c4 & 31);
        u64 q0, q1;
        for (;;) {
            q0 = ldq(pb + c4);
            q1 = ldq(pb + i1);
            if (__all((q0 != SENT) && (q1 != SENT))) break;
            __builtin_amdgcn_s_sleep(1);
        }
        asm volatile("" ::: "memory");
        union { u64 q; float f[2]; } a;
        a.q = q0;
        g0 = a.f[0]; g1 = a.f[1];
        a.q = q1;
        if (c4 < 32) { g0 += a.f[0]; g1 += a.f[1]; }
        wavesum2(g0, g1);
    };
    // scale acquisition: wave 1 polls LLC; everyone else spins on the LDS stamp
    auto getscale = [&](int s) {
        if (trow == 1) {
            pollwide(s);
            if (c4 == 0) { sG[0] = g0; sG[1] = g1; }
            asm volatile("s_waitcnt lgkmcnt(0)" ::: "memory");
            __builtin_amdgcn_sched_barrier(0);
            if (c4 == 0) sStamp = (unsigned)s;
        } else {
            while (sStamp < (unsigned)s) __builtin_amdgcn_s_sleep(0);
            asm volatile("" ::: "memory");
            g0 = sG[0]; g1 = sG[1];
        }
    };
    auto wavenorm = [&]() {
        float pa0 = dot4(v0c, v0c), pa1 = dot4(v1c, v1c);
        wavesum2(pa0, pa1);
        if (c4 == 0) pw[trow] = make_float2(pa0, pa1);
    };
    auto pubparts = [&](int s) {
        if (tid == 0) {
            float q0 = 0.f, q1 = 0.f;
            #pragma unroll
            for (int w = 0; w < 8; ++w) { q0 += pw[w].x; q1 += pw[w].y; }
            union { float f[2]; u64 q; } pk; pk.f[0] = q0; pk.f[1] = q1;
            stq(parts + (size_t)s * NBLK + blk, pk.q);
        }
    };
    // expansion: pieces of x_next, v_next; B2 inside; no trailing barrier (B3 removed:
    // sxt read->next-write ordered by next B1; sv0 read->next-write ordered by B2)
    auto expand = [&](u64* hb, bool pub) {
        const float inv = 1.f / (1.f + tau), tin = tau * inv, opc = 1.f + chi;
        float4 xtP, xtA, xtB;
        {
            float4 vm = (trow > 0) ? ((float4*)(sv0 + (trow - 1) * 256))[c4] : vmtop;
            float4 NT0 = nth(vm, gh > 0, v0c, gh < Hh - 1);
            float4 NT1 = ntw(v1c, c4);
            float4 BASE = f4s(f4fma(tau, yv, xcur), inv);
            float4 xA = f4s(NT0, -tin), xB = f4s(NT1, -tin);
            xpP = BASE; xpA = xA; xpB = xB;
            xtP = f4fma(-chi, xcur, f4s(BASE, opc));
            xtA = f4s(xA, opc);
            xtB = f4s(xB, opc);
            if (trow >= 1) {
                ((float4*)(sxtP + trow * 256))[c4] = xtP;
                ((float4*)(sxtA + trow * 256))[c4] = xtA;
                ((float4*)(sxtB + trow * 256))[c4] = xtB;
            }
            if (pub && trow == 0) {
                u64* rbase = hb + ((size_t)blk * BROWS) * ROWQ;
                pub4(rbase +  9 * ROWQ + 2 * c4, BASE);
                pub4(rbase + 10 * ROWQ + 2 * c4, xA);
                pub4(rbase + 11 * ROWQ + 2 * c4, xB);
            }
        }
        // halo row r0+8 recompute: WAVE 7, vmh = own v0c (bit-exact), xt pieces in regs
        if (trow == 7 && tile < 31) {
            float4 NT0h = nth(v0c, true, v0h, true);
            float4 NT1h = ntw(v1h, c4);
            float4 BASEh = f4s(f4fma(tau, yh, xoh), inv);
            xt8P = f4fma(-chi, xoh, f4s(BASEh, opc));
            xt8A = f4s(f4s(NT0h, -tin), opc);
            xt8B = f4s(f4s(NT1h, -tin), opc);
        }
        barld();   // B2: xt pieces visible
        float4 dhP = mk4(0, 0, 0, 0), dhA = dhP, dhB = dhP;
        if (trow < 7) {
            dhP = f4sub(((float4*)(sxtP + (trow + 1) * 256))[c4], xtP);
            dhA = f4sub(((float4*)(sxtA + (trow + 1) * 256))[c4], xtA);
            dhB = f4sub(((float4*)(sxtB + (trow + 1) * 256))[c4], xtB);
        } else if (tile < 31) {    // trow==7, gh<Hh-1
            dhP = f4sub(xt8P, xtP);
            dhA = f4sub(xt8A, xtA);
            dhB = f4sub(xt8B, xtB);
        }
        float4 dwP = gradw(xtP, c4), dwA = gradw(xtA, c4), dwB = gradw(xtB, c4);
        p0P = f4s(dhP, sigs); p0A = f4fma(sigs, dhA, v0c); p0B = f4s(dhB, sigs);
        p1P = f4s(dwP, sigs); p1A = f4s(dwA, sigs); p1B = f4fma(sigs, dwB, v1c);
        if (pub) {
            u64* rbase = hb + ((size_t)blk * BROWS) * ROWQ;
            if (trow == 0) {
                pub4(rbase + 3 * ROWQ + 2 * c4, p0P);
                pub4(rbase + 4 * ROWQ + 2 * c4, p0A);
                pub4(rbase + 5 * ROWQ + 2 * c4, p0B);
                pub4(rbase + 6 * ROWQ + 2 * c4, p1P);
                pub4(rbase + 7 * ROWQ + 2 * c4, p1A);
                pub4(rbase + 8 * ROWQ + 2 * c4, p1B);
            } else if (trow == 7) {
                pub4(rbase + 0 * ROWQ + 2 * c4, p0P);
                pub4(rbase + 1 * ROWQ + 2 * c4, p0A);
                pub4(rbase + 2 * ROWQ + 2 * c4, p0B);
            }
        }
        // (no B3)
    };

    // ================= INIT (iteration 0): concrete x_0=y, v_1 = nabla(y) =================
    {
        if (tid == 0) sStamp = 0u;            // before B1 -> ordered for all waves
        yv = ld4(y, j4);
        xcur = yv;
        v0c = (gh < Hh - 1) ? f4sub(ld4(y, j4 + 64), yv) : mk4(0, 0, 0, 0);
        v1c = gradw(yv, c4);
        ((float4*)(sv0 + trow * 256))[c4] = v0c;
        if (trow == 7 && tile < 31) {
            const int j4h = bc * 16384 + (r0 + 8) * 64 + c4;
            yh = ld4(y, j4h);
            v0h = f4sub(ld4(y, j4h + 64), yh);
            v1h = gradw(yh, c4);
            xoh = yh;
        }
        if (trow == 0 && tile > 0) {
            float4 ym = ld4(y, bc * 16384 + (r0 - 1) * 64 + c4);
            vmtop = f4sub(yv, ym);
        }
        wavenorm();                           // ||v_1||^2 per-wave partials
        chi = 1.f / sqrtf(1.f + tau);         // chi_0
        sigs = sig / chi;                     // sigma_1
        barld();                              // B1: sv0 + pw + sStamp init visible
        pubparts(1);
        expand(slotp(0), true);               // pieces of x_1, v_2 -> slot 0 (B2 inside)
        tau *= chi; sig = sigs;
    }

    // ================= MAIN LOOP (s = 1..49) =================
    for (int s = 1; s < KSTEPS; ++s) {
        getscale(s);                          // wave 1 polls LLC; others via LDS stamp
        const float al = lamb / fmaxf(sqrtf(g0), lamb);
        const float be = lamb / fmaxf(sqrtf(g1), lamb);
        chi = 1.f / sqrtf(1.f + tau);
        sigs = sig / chi;
        // collapse own row -> concrete x_s, v_{s+1}
        xcur = col3(xpP, xpA, xpB, al, be);
        v0c  = col3(p0P, p0A, p0B, al, be);
        v1c  = col3(p1P, p1A, p1B, al, be);
        ((float4*)(sv0 + trow * 256))[c4] = v0c;
        // halo polls: WAVE 0 = vmtop (6 words), WAVE 7 = bottom halo (18 words)
        u64* hbp = slotp((s - 1) % 3);
        if (trow == 0 && tile > 0) {
            const u64* ra = hbp + ((size_t)(blk - 1) * BROWS) * ROWQ + 2 * c4;
            u64 a0, a1, a2, a3, a4, a5;
            for (;;) {
                a0 = ldq(ra);            a1 = ldq(ra + 1);
                a2 = ldq(ra + ROWQ);     a3 = ldq(ra + ROWQ + 1);
                a4 = ldq(ra + 2 * ROWQ); a5 = ldq(ra + 2 * ROWQ + 1);
                if (__all((a0 != SENT) && (a1 != SENT) && (a2 != SENT) &&
                          (a3 != SENT) && (a4 != SENT) && (a5 != SENT))) break;
                __builtin_amdgcn_s_sleep(1);
            }
            vmtop = col3(unp(a0, a1), unp(a2, a3), unp(a4, a5), al, be);
        } else if (trow == 0) {
            vmtop = mk4(0, 0, 0, 0);
        }
        if (trow == 7 && tile < 31) {
            const u64* rb = hbp + ((size_t)(blk + 1) * BROWS) * ROWQ + 2 * c4;
            u64 b0, b1, b2, b3, b4, b5, b6, b7, b8, b9, b10, b11, b12, b13, b14, b15, b16, b17;
            for (;;) {
                b0  = ldq(rb + 3 * ROWQ);  b1  = ldq(rb + 3 * ROWQ + 1);
                b2  = ldq(rb + 4 * ROWQ);  b3  = ldq(rb + 4 * ROWQ + 1);
                b4  = ldq(rb + 5 * ROWQ);  b5  = ldq(rb + 5 * ROWQ + 1);
                b6  = ldq(rb + 6 * ROWQ);  b7  = ldq(rb + 6 * ROWQ + 1);
                b8  = ldq(rb + 7 * ROWQ);  b9  = ldq(rb + 7 * ROWQ + 1);
                b10 = ldq(rb + 8 * ROWQ);  b11 = ldq(rb + 8 * ROWQ + 1);
                b12 = ldq(rb + 9 * ROWQ);  b13 = ldq(rb + 9 * ROWQ + 1);
                b14 = ldq(rb + 10 * ROWQ); b15 = ldq(rb + 10 * ROWQ + 1);
                b16 = ldq(rb + 11 * ROWQ); b17 = ldq(rb + 11 * ROWQ + 1);
                bool ok = (b0 != SENT) && (b1 != SENT) && (b2 != SENT) && (b3 != SENT) &&
                          (b4 != SENT) && (b5 != SENT) && (b6 != SENT) && (b7 != SENT) &&
                          (b8 != SENT) && (b9 != SENT) && (b10 != SENT) && (b11 != SENT) &&
                          (b12 != SENT) && (b13 != SENT) && (b14 != SENT) && (b15 != SENT) &&
                          (b16 != SENT) && (b17 != SENT);
                if (__all(ok)) break;
                __builtin_amdgcn_s_sleep(1);
            }
            v0h = col3(unp(b0, b1),   unp(b2, b3),   unp(b4, b5),   al, be);
            v1h = col3(unp(b6, b7),   unp(b8, b9),   unp(b10, b11), al, be);
            xoh = col3(unp(b12, b13), unp(b14, b15), unp(b16, b17), al, be);
        }
        asm volatile("" ::: "memory");
        // resets of slot (s+1)%3 (holds step s-2 pieces; all readers done: parts[s] gate);
        // same-wave reset -> republish ordering preserved (wave 0: rows 3-11, wave 7: 0-2)
        {
            u64* rb2 = slotp((s + 1) % 3) + ((size_t)blk * BROWS) * ROWQ;
            if (trow == 0) {
                #pragma unroll
                for (int r = 3; r < 12; ++r) {
                    stq(rb2 + r * ROWQ + 2 * c4, SENT);
                    stq(rb2 + r * ROWQ + 2 * c4 + 1, SENT);
                }
            } else if (trow == 7) {
                #pragma unroll
                for (int r = 0; r < 3; ++r) {
                    stq(rb2 + r * ROWQ + 2 * c4, SENT);
                    stq(rb2 + r * ROWQ + 2 * c4 + 1, SENT);
                }
            }
        }
        wavenorm();                           // ||v_{s+1}||^2 per-wave partials
        barld();                              // B1: sv0 + pw visible
        pubparts(s + 1);
        expand(slotp(s % 3), s < KSTEPS - 1); // pieces of x_{s+1}, v_{s+2} (B2 inside)
        tau *= chi; sig = sigs;
    }

    // ================= FINAL (step 50) =================
    {
        // gate + scales: parts[50] complete => all blocks past B1 of iter 49
        //   => past their top-of-49 slot reads => safe to overwrite h0/h1 with outputs
        getscale(KSTEPS);
        const float a50 = lamb / fmaxf(sqrtf(g0), lamb);
        const float b50 = lamb / fmaxf(sqrtf(g1), lamb);
        float4 x50 = col3(xpP, xpA, xpB, a50, b50);       // x_50 pieces from iter 49
        float4 xt50 = f4fma(-chi, xcur, f4s(x50, 1.f + chi));  // xcur = x_49, chi = chi_49
        const int iv4 = bc * 32768 + gh * 64 + c4;
        st4(xout, j4, x50);
        st4(xtout, j4, xt50);
        st4(uout, iv4, f4s(v0c, a50));                    // u_50 = s_50 * v_50
        st4(uout, iv4 + 16384, f4s(v1c, b50));
    }
}

extern "C" void kernel_launch(void* const* d_in, const int* in_sizes, int n_in,
                              void* d_out, int out_size, void* d_ws, size_t ws_size,
                              hipStream_t stream) {
    (void)in_sizes; (void)n_in; (void)out_size; (void)ws_size;
    const float* y     = (const float*)d_in[0];
    const float* lambd = (const float*)d_in[1];
    float* xout  = (float*)d_out;       // [0, NX)
    float* xtout = xout + NX;           // [NX, 2NX)
    float* uout  = xout + 2 * NX;       // [2NX, 2NX+NU)

    // piece slots 0,1 live in d_out (4.72 MB <= 6.29 MB; all piece reads complete
    // before final output writes, gated by the parts[50] poll). slot 2 + parts in d_ws.
    u64* h0 = (u64*)d_out;
    u64* h1 = h0 + SLOTQ;
    u64* h2 = (u64*)d_ws;
    u64* parts = h2 + SLOTQ;            // [(KSTEPS+1)][NBLK] u64

    init_ws<<<SLOTQ / 256, 256, 0, stream>>>(h0, h1, h2, parts);
    cp_persist<<<NBLK, 512, 0, stream>>>(y, lambd, xout, xtout, uout, h0, h1, h2, parts);
}

// Round 19
// 189.728 us; speedup vs baseline: 1.0280x; 1.0280x over previous
//
#include <hip/hip_runtime.h>
#include <math.h>

constexpr int Cc = 3, Hh = 256;
constexpr int NX = 393216;                 // 2*3*256*256
constexpr int R = 8;                       // rows per block
constexpr int NBLK = 192;                  // 6 images * 32 tiles (1 block/CU)
constexpr int KSTEPS = 50;
constexpr int ROWQ = 128;                  // u64 per halo row (256 floats)
constexpr int BROWS = 12;                  // halo rows per block per slot
constexpr int SLOTQ = NBLK * BROWS * ROWQ; // u64 per slot

using u64 = unsigned long long;
constexpr u64 SENT = 0x8000000080000000ull;  // (-0.0f,-0.0f): unreachable payload

__device__ __forceinline__ float4 ld4(const float* p, int i) { return ((const float4*)p)[i]; }
__device__ __forceinline__ void st4(float* p, int i, float4 v) { ((float4*)p)[i] = v; }
__device__ __forceinline__ float4 mk4(float a, float b, float c, float d) { return make_float4(a, b, c, d); }
__device__ __forceinline__ u64 ldq(const u64* p) {
    return __hip_atomic_load(p, __ATOMIC_RELAXED, __HIP_MEMORY_SCOPE_AGENT);
}
__device__ __forceinline__ void stq(u64* p, u64 v) {
    __hip_atomic_store(p, v, __ATOMIC_RELAXED, __HIP_MEMORY_SCOPE_AGENT);
}
__device__ __forceinline__ void pub4(u64* w, float4 v) {
    union { float f[2]; u64 q; } a, b;
    a.f[0] = v.x; a.f[1] = v.y; b.f[0] = v.z; b.f[1] = v.w;
    stq(w, a.q); stq(w + 1, b.q);
}
__device__ __forceinline__ float4 unp(u64 lo, u64 hi) {
    union { u64 q; float f[2]; } a, b; a.q = lo; b.q = hi;
    return make_float4(a.f[0], a.f[1], b.f[0], b.f[1]);
}
__device__ __forceinline__ float4 col3(float4 P, float4 A, float4 B, float a, float b) {
    return mk4(fmaf(a, A.x, fmaf(b, B.x, P.x)), fmaf(a, A.y, fmaf(b, B.y, P.y)),
               fmaf(a, A.z, fmaf(b, B.z, P.z)), fmaf(a, A.w, fmaf(b, B.w, P.w)));
}
__device__ __forceinline__ float4 f4sub(float4 a, float4 b) {
    return mk4(a.x - b.x, a.y - b.y, a.z - b.z, a.w - b.w);
}
__device__ __forceinline__ float4 f4s(float4 a, float s) {
    return mk4(a.x * s, a.y * s, a.z * s, a.w * s);
}
__device__ __forceinline__ float4 f4fma(float s, float4 a, float4 b) {   // s*a + b
    return mk4(fmaf(s, a.x, b.x), fmaf(s, a.y, b.y), fmaf(s, a.z, b.z), fmaf(s, a.w, b.w));
}
__device__ __forceinline__ float4 nth(float4 vm, bool up, float4 v0x, bool dn) {
    return mk4((up ? vm.x : 0.f) - (dn ? v0x.x : 0.f), (up ? vm.y : 0.f) - (dn ? v0x.y : 0.f),
               (up ? vm.z : 0.f) - (dn ? v0x.z : 0.f), (up ? vm.w : 0.f) - (dn ? v0x.w : 0.f));
}
__device__ __forceinline__ float4 ntw(float4 v1x, int c4) {
    float ul = __shfl_up(v1x.w, 1, 64);
    return mk4(((c4 > 0) ? ul : 0.f) - v1x.x, v1x.x - v1x.y, v1x.y - v1x.z,
               v1x.z - ((c4 < 63) ? v1x.w : 0.f));
}
__device__ __forceinline__ float4 gradw(float4 t, int c4) {
    float xn = __shfl_down(t.x, 1, 64);
    return mk4(t.y - t.x, t.z - t.y, t.w - t.z, (c4 < 63) ? (xn - t.w) : 0.f);
}
__device__ __forceinline__ float dot4(float4 a, float4 b) {
    return a.x * b.x + a.y * b.y + a.z * b.z + a.w * b.w;
}
__device__ __forceinline__ void barld() {
    asm volatile("s_waitcnt lgkmcnt(0)" ::: "memory");
    __builtin_amdgcn_sched_barrier(0);
    __builtin_amdgcn_s_barrier();
    __builtin_amdgcn_sched_barrier(0);
}

__global__ void init_ws(u64* h0, u64* h1, u64* h2, u64* parts) {
    int i = blockIdx.x * 256 + threadIdx.x;
    if (i < SLOTQ) { h0[i] = SENT; h1[i] = SENT; h2[i] = SENT; }
    if (i < (KSTEPS + 1) * NBLK) parts[i] = SENT;
}

__global__ void __launch_bounds__(512, 1) cp_persist(
    const float* __restrict__ y, const float* __restrict__ lambd,
    float* __restrict__ xout, float* __restrict__ xtout, float* __restrict__ uout,
    u64* __restrict__ h0, u64* __restrict__ h1, u64* __restrict__ h2,
    u64* __restrict__ parts)
{
    __shared__ float sv0[8 * 256];
    __shared__ float sxtP[8 * 256], sxtA[8 * 256], sxtB[8 * 256];
    __shared__ float2 pw[8];

    const int tid = threadIdx.x, blk = blockIdx.x;
    const int bc = blk >> 5, tile = blk & 31, r0 = tile * R;
    const int c4 = tid & 63, trow = tid >> 6;      // one row per wave
    const int b = (bc >= Cc) ? 1 : 0;
    const float lamb = expf(lambd[0]);
    const int gh = r0 + trow;
    const int j4 = bc * 16384 + gh * 64 + c4;

    float4 yv, xcur, v0c, v1c;
    float4 xpP, xpA, xpB, p0P, p0A, p0B, p1P, p1A, p1B;
    float4 yh = mk4(0, 0, 0, 0), vmtop = yh, v0h = yh, v1h = yh, xoh = yh;
    float4 xt8P = yh, xt8A = yh, xt8B = yh;        // wave-7 halo xt pieces (registers)
    float tau = 0.20412414523193150818f, sig = tau, chi = 0.f, sigs = 0.f;
    float g0 = 0.f, g1 = 0.f;

    auto slotp = [&](int r) -> u64* { return (r == 0) ? h0 : ((r == 1) ? h1 : h2); };
    auto wavesum2 = [&](float& a, float& bb) {
        #pragma unroll
        for (int m = 1; m < 64; m <<= 1) { a += __shfl_xor(a, m, 64); bb += __shfl_xor(bb, m, 64); }
    };

    // parts poll (all waves): 2 words/lane, fixed-order deterministic sum
    auto pollscale = [&](int s) {
        const u64* pb = parts + (size_t)s * NBLK + b * 96;
        const int i1 = 64 + (c4 & 31);
        u64 q0, q1;
        for (;;) {
            q0 = ldq(pb + c4);
            q1 = ldq(pb + i1);
            if (__all((q0 != SENT) && (q1 != SENT))) break;
            __builtin_amdgcn_s_sleep(1);
        }
        asm volatile("" ::: "memory");
        union { u64 q; float f[2]; } a;
        a.q = q0;
        g0 = a.f[0]; g1 = a.f[1];
        a.q = q1;
        if (c4 < 32) { g0 += a.f[0]; g1 += a.f[1]; }
        wavesum2(g0, g1);
    };
    // per-wave norm -> LDS (pre-B1)
    auto wavenorm = [&]() {
        float pa0 = dot4(v0c, v0c), pa1 = dot4(v1c, v1c);
        wavesum2(pa0, pa1);
        if (c4 == 0) pw[trow] = make_float2(pa0, pa1);
    };
    // block-sum publish (post-B1; one u64 per block)
    auto pubparts = [&](int s) {
        if (tid == 0) {
            float q0 = 0.f, q1 = 0.f;
            #pragma unroll
            for (int w = 0; w < 8; ++w) { q0 += pw[w].x; q1 += pw[w].y; }
            union { float f[2]; u64 q; } pk; pk.f[0] = q0; pk.f[1] = q1;
            stq(parts + (size_t)s * NBLK + blk, pk.q);
        }
    };
    // expansion: pieces of x_next, v_next; B2 inside; NO trailing barrier (B3 removed:
    // sxt read->next-write ordered by next B1; sv0 read->next-write ordered by B2)
    auto expand = [&](u64* hb, bool pub) {
        const float inv = 1.f / (1.f + tau), tin = tau * inv, opc = 1.f + chi;
        float4 xtP, xtA, xtB;
        {
            float4 vm = (trow > 0) ? ((float4*)(sv0 + (trow - 1) * 256))[c4] : vmtop;
            float4 NT0 = nth(vm, gh > 0, v0c, gh < Hh - 1);
            float4 NT1 = ntw(v1c, c4);
            float4 BASE = f4s(f4fma(tau, yv, xcur), inv);
            float4 xA = f4s(NT0, -tin), xB = f4s(NT1, -tin);
            xpP = BASE; xpA = xA; xpB = xB;
            xtP = f4fma(-chi, xcur, f4s(BASE, opc));
            xtA = f4s(xA, opc);
            xtB = f4s(xB, opc);
            if (trow >= 1) {
                ((float4*)(sxtP + trow * 256))[c4] = xtP;
                ((float4*)(sxtA + trow * 256))[c4] = xtA;
                ((float4*)(sxtB + trow * 256))[c4] = xtB;
            }
            if (pub && trow == 0) {
                u64* rbase = hb + ((size_t)blk * BROWS) * ROWQ;
                pub4(rbase +  9 * ROWQ + 2 * c4, BASE);
                pub4(rbase + 10 * ROWQ + 2 * c4, xA);
                pub4(rbase + 11 * ROWQ + 2 * c4, xB);
            }
        }
        // halo row r0+8 recompute: WAVE 7, vmh = own v0c (== old sv0[7], bit-exact),
        // xt pieces stay in registers (only wave 7 consumes them in pass 2)
        if (trow == 7 && tile < 31) {
            float4 NT0h = nth(v0c, true, v0h, true);
            float4 NT1h = ntw(v1h, c4);
            float4 BASEh = f4s(f4fma(tau, yh, xoh), inv);
            xt8P = f4fma(-chi, xoh, f4s(BASEh, opc));
            xt8A = f4s(f4s(NT0h, -tin), opc);
            xt8B = f4s(f4s(NT1h, -tin), opc);
        }
        barld();   // B2: xt pieces visible
        float4 dhP = mk4(0, 0, 0, 0), dhA = dhP, dhB = dhP;
        if (trow < 7) {
            dhP = f4sub(((float4*)(sxtP + (trow + 1) * 256))[c4], xtP);
            dhA = f4sub(((float4*)(sxtA + (trow + 1) * 256))[c4], xtA);
            dhB = f4sub(((float4*)(sxtB + (trow + 1) * 256))[c4], xtB);
        } else if (tile < 31) {    // trow==7, gh<Hh-1
            dhP = f4sub(xt8P, xtP);
            dhA = f4sub(xt8A, xtA);
            dhB = f4sub(xt8B, xtB);
        }
        float4 dwP = gradw(xtP, c4), dwA = gradw(xtA, c4), dwB = gradw(xtB, c4);
        p0P = f4s(dhP, sigs); p0A = f4fma(sigs, dhA, v0c); p0B = f4s(dhB, sigs);
        p1P = f4s(dwP, sigs); p1A = f4s(dwA, sigs); p1B = f4fma(sigs, dwB, v1c);
        if (pub) {
            u64* rbase = hb + ((size_t)blk * BROWS) * ROWQ;
            if (trow == 0) {
                pub4(rbase + 3 * ROWQ + 2 * c4, p0P);
                pub4(rbase + 4 * ROWQ + 2 * c4, p0A);
                pub4(rbase + 5 * ROWQ + 2 * c4, p0B);
                pub4(rbase + 6 * ROWQ + 2 * c4, p1P);
                pub4(rbase + 7 * ROWQ + 2 * c4, p1A);
                pub4(rbase + 8 * ROWQ + 2 * c4, p1B);
            } else if (trow == 7) {
                pub4(rbase + 0 * ROWQ + 2 * c4, p0P);
                pub4(rbase + 1 * ROWQ + 2 * c4, p0A);
                pub4(rbase + 2 * ROWQ + 2 * c4, p0B);
            }
        }
        // (no B3)
    };

    // ================= INIT (iteration 0): concrete x_0=y, v_1 = nabla(y) =================
    {
        yv = ld4(y, j4);
        xcur = yv;
        v0c = (gh < Hh - 1) ? f4sub(ld4(y, j4 + 64), yv) : mk4(0, 0, 0, 0);
        v1c = gradw(yv, c4);
        ((float4*)(sv0 + trow * 256))[c4] = v0c;
        if (trow == 7 && tile < 31) {
            const int j4h = bc * 16384 + (r0 + 8) * 64 + c4;
            yh = ld4(y, j4h);
            v0h = f4sub(ld4(y, j4h + 64), yh);
            v1h = gradw(yh, c4);
            xoh = yh;
        }
        if (trow == 0 && tile > 0) {
            float4 ym = ld4(y, bc * 16384 + (r0 - 1) * 64 + c4);
            vmtop = f4sub(yv, ym);
        }
        wavenorm();                           // ||v_1||^2 per-wave partials
        chi = 1.f / sqrtf(1.f + tau);         // chi_0
        sigs = sig / chi;                     // sigma_1
        barld();                              // B1: sv0 + pw visible
        pubparts(1);
        expand(slotp(0), true);               // pieces of x_1, v_2 -> slot 0 (B2 inside)
        tau *= chi; sig = sigs;
    }

    // ================= MAIN LOOP (s = 1..49) =================
    for (int s = 1; s < KSTEPS; ++s) {
        pollscale(s);                         // scales of step s (published 1 iter ago -> hit)
        const float al = lamb / fmaxf(sqrtf(g0), lamb);
        const float be = lamb / fmaxf(sqrtf(g1), lamb);
        chi = 1.f / sqrtf(1.f + tau);
        sigs = sig / chi;
        // collapse own row -> concrete x_s, v_{s+1}
        xcur = col3(xpP, xpA, xpB, al, be);
        v0c  = col3(p0P, p0A, p0B, al, be);
        v1c  = col3(p1P, p1A, p1B, al, be);
        ((float4*)(sv0 + trow * 256))[c4] = v0c;
        // halo polls: WAVE 0 = vmtop (6 words), WAVE 7 = bottom halo (18 words)
        u64* hbp = slotp((s - 1) % 3);
        if (trow == 0 && tile > 0) {
            const u64* ra = hbp + ((size_t)(blk - 1) * BROWS) * ROWQ + 2 * c4;
            u64 a0, a1, a2, a3, a4, a5;
            for (;;) {
                a0 = ldq(ra);            a1 = ldq(ra + 1);
                a2 = ldq(ra + ROWQ);     a3 = ldq(ra + ROWQ + 1);
                a4 = ldq(ra + 2 * ROWQ); a5 = ldq(ra + 2 * ROWQ + 1);
                if (__all((a0 != SENT) && (a1 != SENT) && (a2 != SENT) &&
                          (a3 != SENT) && (a4 != SENT) && (a5 != SENT))) break;
                __builtin_amdgcn_s_sleep(1);
            }
            vmtop = col3(unp(a0, a1), unp(a2, a3), unp(a4, a5), al, be);
        } else if (trow == 0) {
            vmtop = mk4(0, 0, 0, 0);
        }
        if (trow == 7 && tile < 31) {
            const u64* rb = hbp + ((size_t)(blk + 1) * BROWS) * ROWQ + 2 * c4;
            u64 b0, b1, b2, b3, b4, b5, b6, b7, b8, b9, b10, b11, b12, b13, b14, b15, b16, b17;
            for (;;) {
                b0  = ldq(rb + 3 * ROWQ);  b1  = ldq(rb + 3 * ROWQ + 1);
                b2  = ldq(rb + 4 * ROWQ);  b3  = ldq(rb + 4 * ROWQ + 1);
                b4  = ldq(rb + 5 * ROWQ);  b5  = ldq(rb + 5 * ROWQ + 1);
                b6  = ldq(rb + 6 * ROWQ);  b7  = ldq(rb + 6 * ROWQ + 1);
                b8  = ldq(rb + 7 * ROWQ);  b9  = ldq(rb + 7 * ROWQ + 1);
                b10 = ldq(rb + 8 * ROWQ);  b11 = ldq(rb + 8 * ROWQ + 1);
                b12 = ldq(rb + 9 * ROWQ);  b13 = ldq(rb + 9 * ROWQ + 1);
                b14 = ldq(rb + 10 * ROWQ); b15 = ldq(rb + 10 * ROWQ + 1);
                b16 = ldq(rb + 11 * ROWQ); b17 = ldq(rb + 11 * ROWQ + 1);
                bool ok = (b0 != SENT) && (b1 != SENT) && (b2 != SENT) && (b3 != SENT) &&
                          (b4 != SENT) && (b5 != SENT) && (b6 != SENT) && (b7 != SENT) &&
                          (b8 != SENT) && (b9 != SENT) && (b10 != SENT) && (b11 != SENT) &&
                          (b12 != SENT) && (b13 != SENT) && (b14 != SENT) && (b15 != SENT) &&
                          (b16 != SENT) && (b17 != SENT);
                if (__all(ok)) break;
                __builtin_amdgcn_s_sleep(1);
            }
            v0h = col3(unp(b0, b1),   unp(b2, b3),   unp(b4, b5),   al, be);
            v1h = col3(unp(b6, b7),   unp(b8, b9),   unp(b10, b11), al, be);
            xoh = col3(unp(b12, b13), unp(b14, b15), unp(b16, b17), al, be);
        }
        asm volatile("" ::: "memory");
        // resets of slot (s+1)%3 (holds step s-2 pieces; all readers done: parts[s] gate);
        // same-wave reset -> republish ordering preserved (wave 0: rows 3-11, wave 7: 0-2)
        {
            u64* rb2 = slotp((s + 1) % 3) + ((size_t)blk * BROWS) * ROWQ;
            if (trow == 0) {
                #pragma unroll
                for (int r = 3; r < 12; ++r) {
                    stq(rb2 + r * ROWQ + 2 * c4, SENT);
                    stq(rb2 + r * ROWQ + 2 * c4 + 1, SENT);
                }
            } else if (trow == 7) {
                #pragma unroll
                for (int r = 0; r < 3; ++r) {
                    stq(rb2 + r * ROWQ + 2 * c4, SENT);
                    stq(rb2 + r * ROWQ + 2 * c4 + 1, SENT);
                }
            }
        }
        wavenorm();                           // ||v_{s+1}||^2 per-wave partials
        barld();                              // B1: sv0 + pw visible
        pubparts(s + 1);
        expand(slotp(s % 3), s < KSTEPS - 1); // pieces of x_{s+1}, v_{s+2} (B2 inside)
        tau *= chi; sig = sigs;
    }

    // ================= FINAL (step 50) =================
    {
        // gate + scales: parts[50] complete => all blocks past B1 of iter 49
        //   => past their top-of-49 slot reads => safe to overwrite h0/h1 with outputs
        pollscale(KSTEPS);
        const float a50 = lamb / fmaxf(sqrtf(g0), lamb);
        const float b50 = lamb / fmaxf(sqrtf(g1), lamb);
        float4 x50 = col3(xpP, xpA, xpB, a50, b50);       // x_50 pieces from iter 49
        float4 xt50 = f4fma(-chi, xcur, f4s(x50, 1.f + chi));  // xcur = x_49, chi = chi_49
        const int iv4 = bc * 32768 + gh * 64 + c4;
        st4(xout, j4, x50);
        st4(xtout, j4, xt50);
        st4(uout, iv4, f4s(v0c, a50));                    // u_50 = s_50 * v_50
        st4(uout, iv4 + 16384, f4s(v1c, b50));
    }
}

extern "C" void kernel_launch(void* const* d_in, const int* in_sizes, int n_in,
                              void* d_out, int out_size, void* d_ws, size_t ws_size,
                              hipStream_t stream) {
    (void)in_sizes; (void)n_in; (void)out_size; (void)ws_size;
    const float* y     = (const float*)d_in[0];
    const float* lambd = (const float*)d_in[1];
    float* xout  = (float*)d_out;       // [0, NX)
    float* xtout = xout + NX;           // [NX, 2NX)
    float* uout  = xout + 2 * NX;       // [2NX, 2NX+NU)

    // piece slots 0,1 live in d_out (4.72 MB <= 6.29 MB; all piece reads complete
    // before final output writes, gated by the parts[50] poll). slot 2 + parts in d_ws.
    u64* h0 = (u64*)d_out;
    u64* h1 = h0 + SLOTQ;
    u64* h2 = (u64*)d_ws;
    u64* parts = h2 + SLOTQ;            // [(KSTEPS+1)][NBLK] u64

    init_ws<<<SLOTQ / 256, 256, 0, stream>>>(h0, h1, h2, parts);
    cp_persist<<<NBLK, 512, 0, stream>>>(y, lambd, xout, xtout, uout, h0, h1, h2, parts);
}